// Round 13
// baseline (61.923 us; speedup 1.0000x reference)
//
#include <hip/hip_runtime.h>

// ADDA local attention, K=3, dilation=1, head_dim=64.
// q,k,v = [B=8, d=512, H=56, W=56] fp32 (channel-major), out = [B,H,W,512] fp32.
//
// R13 = R12 + 2-way channel split to break the 14-waves/CU grid cap:
//  wave = (row, channel-half). Pass-1 partial logits over 32 ch, partner
//  halves summed via small LDS buffer (one barrier). Softmax redundant.
//  Pass-2 over own 32 ch; per-wave LDS transpose in px-batches of 24/24/8
//  so every output run is 32 ch = 128 B = one full line (zero inflation).
//  Grid 1792 x 4 waves = 28 waves/CU (7 blocks/CU exactly; LDS 21.9KB x7 fits).

namespace {

constexpr int HD = 64, HH = 56, WW = 56, HW = HH * WW;
constexpr int CS = HW, DTOT = 512;
constexpr float SCALE = 0.125f;
constexpr int NB   = HH / 2;   // 28 bands (2 rows per block)
constexpr int TSTR = 33;       // transpose row stride, gcd(33,32)=1
constexpr int TPX  = 24;       // px per transpose batch (24,24,8)

// value of this row at x-1 (lane i <- lane i-1): wave_shr:1 = 0x138
__device__ __forceinline__ float tapL(float v) {
  int i = __float_as_int(v);
  return __int_as_float(__builtin_amdgcn_update_dpp(i, i, 0x138, 0xF, 0xF, false));
}
// value of this row at x+1 (lane i <- lane i+1): wave_shl:1 = 0x130
__device__ __forceinline__ float tapR(float v) {
  int i = __float_as_int(v);
  return __int_as_float(__builtin_amdgcn_update_dpp(i, i, 0x130, 0xF, 0xF, false));
}

__global__ __launch_bounds__(256, 6)
void adda_fwd(const float* __restrict__ qg, const float* __restrict__ kg,
              const float* __restrict__ vg, float* __restrict__ outg) {
  __shared__ float lgbuf[4][9][64];        // 9216 B: partial logits
  __shared__ float tbuf[4][TPX * TSTR];    // 12672 B: per-wave transpose

  // XCD-aware bijective swizzle (nwg = 1792 = 8*224): one bh-plane's blocks
  // run consecutively on one XCD -> halo re-reads hit its private L2.
  int wg = (int)blockIdx.x;
  const int nwg = (int)gridDim.x;
  if ((nwg & 7) == 0) wg = (wg & 7) * (nwg >> 3) + (wg >> 3);

  const int band = wg % NB;
  const int bh   = wg / NB;                // b*8 + head
  const int tid  = (int)threadIdx.x;
  const int l    = tid & 63;
  const int wv   = tid >> 6;               // 0..3
  const int r    = wv >> 1;                // row within band
  const int h    = wv & 1;                 // channel half
  const int y    = band * 2 + r;
  const int x    = l < WW ? l : WW - 1;    // lanes 56-63 clone x=55 (unused)

  const long base = (long)bh * HD * HW + (long)(h * 32) * CS;
  const int gym = y > 0 ? y - 1 : 0;       // clamped rows; OOB masked below
  const int gyp = y < HH - 1 ? y + 1 : y;

  const float* __restrict__ qp = qg + base + y * WW + x;
  const float* __restrict__ k0 = kg + base + gym * WW + x;
  const float* __restrict__ k1 = kg + base + y   * WW + x;
  const float* __restrict__ k2 = kg + base + gyp * WW + x;

  // ---- pass 1: partial logits over this wave's 32 channels ----
  float lg[9];
#pragma unroll
  for (int n = 0; n < 9; ++n) lg[n] = 0.f;

#pragma unroll 8
  for (int c = 0; c < 32; ++c) {
    const float qv = qp[c * CS];
    const float a0 = k0[c * CS], a1 = k1[c * CS], a2 = k2[c * CS];
    lg[0] = fmaf(qv, tapL(a0), lg[0]);
    lg[1] = fmaf(qv, a0,       lg[1]);
    lg[2] = fmaf(qv, tapR(a0), lg[2]);
    lg[3] = fmaf(qv, tapL(a1), lg[3]);
    lg[4] = fmaf(qv, a1,       lg[4]);
    lg[5] = fmaf(qv, tapR(a1), lg[5]);
    lg[6] = fmaf(qv, tapL(a2), lg[6]);
    lg[7] = fmaf(qv, a2,       lg[7]);
    lg[8] = fmaf(qv, tapR(a2), lg[8]);
  }

  // ---- sum with partner half (wv^1): 2-way aliasing only, one barrier ----
#pragma unroll
  for (int n = 0; n < 9; ++n) lgbuf[wv][n][l] = lg[n];
  __syncthreads();
#pragma unroll
  for (int n = 0; n < 9; ++n) lg[n] += lgbuf[wv ^ 1][n][l];

  // ---- softmax with zero-padded-unfold masking (OOB logit = exact 0) ----
  const bool okt = y > 0, okb = y < HH - 1, okl = x > 0, okr = x < WW - 1;
  const bool ok[9] = {okt && okl, okt, okt && okr,
                      okl,        true, okr,
                      okb && okl, okb, okb && okr};
  float w[9];
  float mx = 0.f;
#pragma unroll
  for (int n = 0; n < 9; ++n) { w[n] = ok[n] ? lg[n] * SCALE : 0.f; mx = fmaxf(mx, w[n]); }
  float sum = 0.f;
#pragma unroll
  for (int n = 0; n < 9; ++n) { w[n] = __expf(w[n] - mx); sum += w[n]; }
  const float inv = 1.f / sum;
#pragma unroll
  for (int n = 0; n < 9; ++n) w[n] = ok[n] ? w[n] * inv : 0.f;  // OOB v = 0

  // ---- pass 2: weighted V over own 32 channels ----
  const float* __restrict__ v0 = vg + base + gym * WW + x;
  const float* __restrict__ v1 = vg + base + y   * WW + x;
  const float* __restrict__ v2 = vg + base + gyp * WW + x;

  float o[32];
#pragma unroll 8
  for (int c = 0; c < 32; ++c) {
    const float a0 = v0[c * CS], a1 = v1[c * CS], a2 = v2[c * CS];
    float acc;
    acc = w[0] * tapL(a0);
    acc = fmaf(w[1], a0,       acc);
    acc = fmaf(w[2], tapR(a0), acc);
    acc = fmaf(w[3], tapL(a1), acc);
    acc = fmaf(w[4], a1,       acc);
    acc = fmaf(w[5], tapR(a1), acc);
    acc = fmaf(w[6], tapL(a2), acc);
    acc = fmaf(w[7], a2,       acc);
    acc = fmaf(w[8], tapR(a2), acc);
    o[c] = acc;
  }

  // ---- per-wave transpose in px batches (24,24,8); 128B-line output runs ----
  float* __restrict__ tw = &tbuf[wv][0];
  float* __restrict__ ob =
      outg + ((long)(bh >> 3) * HW + y * WW) * DTOT + (bh & 7) * HD + h * 32;

#pragma unroll
  for (int b0 = 0; b0 < WW; b0 += TPX) {
    const int npx = (WW - b0) < TPX ? (WW - b0) : TPX;  // 24,24,8
    // same-wave LDS ops execute in order -> no barrier between batches
    if (l >= b0 && l < b0 + npx) {
      const int lp = l - b0;
#pragma unroll
      for (int i = 0; i < 8; ++i)
        *(float4*)&tw[lp * TSTR + 4 * i] =
            make_float4(o[4 * i], o[4 * i + 1], o[4 * i + 2], o[4 * i + 3]);
    }
    const int nf4 = npx * 8;                            // 192,192,64
    for (int g = l; g < nf4; g += 64) {
      const int pxl = g >> 3, slot = g & 7;
      const float4 t = *(const float4*)&tw[pxl * TSTR + slot * 4];
      *(float4*)(ob + (long)(b0 + pxl) * DTOT + slot * 4) = t;
    }
  }
}

} // namespace

extern "C" void kernel_launch(void* const* d_in, const int* in_sizes, int n_in,
                              void* d_out, int out_size, void* d_ws, size_t ws_size,
                              hipStream_t stream) {
  const float* q = (const float*)d_in[0];
  const float* k = (const float*)d_in[1];
  const float* v = (const float*)d_in[2];
  float* out = (float*)d_out;

  const int BH = in_sizes[0] / (HD * HW);  // B * 8 heads = 64
  dim3 grid(BH * NB);                       // 1792 = 8 * 224
  adda_fwd<<<grid, 256, 0, stream>>>(q, k, v, out);
}

// Round 14
// 39.937 us; speedup vs baseline: 1.5505x; 1.5505x over previous
//
#include <hip/hip_runtime.h>

// ADDA local attention, K=3, dilation=1, head_dim=64.
// q,k,v = [B=8, d=512, H=56, W=56] fp32 (channel-major), out = [B,H,W,512] fp32.
//
// R14 = R12 (row-wave DPP kernel, 44.5 us) + explicit load pipelining:
//  - __launch_bounds__(128,4): VGPR cap 128 (R12's 64 starved MLP)
//  - pass-1/pass-2 in ping-pong batches of 8 channels: issue batch b+1's
//    loads BEFORE consuming batch b -> ~64 loads continuously in flight
//  - first v-batch issued before softmax (latency hides under ~70 VALU ops)
//  - transpose read-out overlaps next half's v loads
// Invariants kept (hard-won): wave owns a pixel's FULL 512B output
// (R13: splitting it 2.14x'd WRITE_SIZE); XCD swizzle (FETCH 102->76 MB);
// zero-padded-unfold masking at softmax only.

namespace {

constexpr int HD = 64, HH = 56, WW = 56, HW = HH * WW;
constexpr int CS = HW, DTOT = 512;
constexpr float SCALE = 0.125f;
constexpr int NB   = HH / 2;   // 28 bands, 2 rows (2 waves) per block
constexpr int TSTR = 36;       // transpose px stride (32 data + 4 pad)

// value of this row at x-1 (lane i <- lane i-1): wave_shr:1 = 0x138
__device__ __forceinline__ float tapL(float v) {
  int i = __float_as_int(v);
  return __int_as_float(__builtin_amdgcn_update_dpp(i, i, 0x138, 0xF, 0xF, false));
}
// value of this row at x+1 (lane i <- lane i+1): wave_shl:1 = 0x130
__device__ __forceinline__ float tapR(float v) {
  int i = __float_as_int(v);
  return __int_as_float(__builtin_amdgcn_update_dpp(i, i, 0x130, 0xF, 0xF, false));
}

__global__ __launch_bounds__(128, 4)
void adda_fwd(const float* __restrict__ qg, const float* __restrict__ kg,
              const float* __restrict__ vg, float* __restrict__ outg) {
  __shared__ float tbuf[2][64 * TSTR];   // 18432 B, per-wave transpose

  // XCD-aware bijective swizzle (nwg = 1792 = 8*224)
  int wg = (int)blockIdx.x;
  const int nwg = (int)gridDim.x;
  if ((nwg & 7) == 0) wg = (wg & 7) * (nwg >> 3) + (wg >> 3);

  const int band = wg % NB;
  const int bh   = wg / NB;              // b*8 + head
  const int l    = (int)threadIdx.x & 63;
  const int wv   = (int)threadIdx.x >> 6;
  const int y    = band * 2 + wv;
  const int x    = l < WW ? l : WW - 1;  // lanes 56-63 clone x=55 (not stored)

  const long base = (long)bh * HD * HW;
  const int gym = y > 0 ? y - 1 : 0;     // clamped rows; OOB masked below
  const int gyp = y < HH - 1 ? y + 1 : y;

  const float* __restrict__ qp = qg + base + y * WW + x;
  const float* __restrict__ k0 = kg + base + gym * WW + x;
  const float* __restrict__ k1 = kg + base + y   * WW + x;
  const float* __restrict__ k2 = kg + base + gyp * WW + x;
  const float* __restrict__ v0 = vg + base + gym * WW + x;
  const float* __restrict__ v1 = vg + base + y   * WW + x;
  const float* __restrict__ v2 = vg + base + gyp * WW + x;

  float lg[9];
#pragma unroll
  for (int n = 0; n < 9; ++n) lg[n] = 0.f;

  // ---- pass 1: ping-pong batches of 8 channels (32 loads in flight/slab) ----
  float qA[8], a0A[8], a1A[8], a2A[8];
  float qB[8], a0B[8], a1B[8], a2B[8];

#define LOADK(S, cb)                                   \
  _Pragma("unroll") for (int i = 0; i < 8; ++i) {      \
    q##S[i]  = qp[((cb) + i) * CS];                    \
    a0##S[i] = k0[((cb) + i) * CS];                    \
    a1##S[i] = k1[((cb) + i) * CS];                    \
    a2##S[i] = k2[((cb) + i) * CS];                    \
  }
#define CONSK(S)                                       \
  _Pragma("unroll") for (int i = 0; i < 8; ++i) {      \
    const float qv = q##S[i];                          \
    lg[0] = fmaf(qv, tapL(a0##S[i]), lg[0]);           \
    lg[1] = fmaf(qv, a0##S[i],       lg[1]);           \
    lg[2] = fmaf(qv, tapR(a0##S[i]), lg[2]);           \
    lg[3] = fmaf(qv, tapL(a1##S[i]), lg[3]);           \
    lg[4] = fmaf(qv, a1##S[i],       lg[4]);           \
    lg[5] = fmaf(qv, tapR(a1##S[i]), lg[5]);           \
    lg[6] = fmaf(qv, tapL(a2##S[i]), lg[6]);           \
    lg[7] = fmaf(qv, a2##S[i],       lg[7]);           \
    lg[8] = fmaf(qv, tapR(a2##S[i]), lg[8]);           \
  }

  LOADK(A, 0);
  LOADK(B, 8);  CONSK(A);
  LOADK(A, 16); CONSK(B);
  LOADK(B, 24); CONSK(A);
  LOADK(A, 32); CONSK(B);
  LOADK(B, 40); CONSK(A);
  LOADK(A, 48); CONSK(B);
  LOADK(B, 56); CONSK(A);

  // ---- v batch 0 issued early: latency hides under softmax VALU ----
  float b0A[8], b1A[8], b2A[8];
  float b0B[8], b1B[8], b2B[8];
#define LOADV(S, cb)                                   \
  _Pragma("unroll") for (int i = 0; i < 8; ++i) {      \
    b0##S[i] = v0[((cb) + i) * CS];                    \
    b1##S[i] = v1[((cb) + i) * CS];                    \
    b2##S[i] = v2[((cb) + i) * CS];                    \
  }
  LOADV(A, 0);
  CONSK(B);  // last k batch

  // ---- softmax with zero-padded-unfold masking (OOB logit = exact 0) ----
  const bool okt = y > 0, okb = y < HH - 1, okl = x > 0, okr = x < WW - 1;
  const bool ok[9] = {okt && okl, okt, okt && okr,
                      okl,        true, okr,
                      okb && okl, okb, okb && okr};
  float w[9];
  float mx = 0.f;   // zeros (OOB logits) participate in the max
#pragma unroll
  for (int n = 0; n < 9; ++n) { w[n] = ok[n] ? lg[n] * SCALE : 0.f; mx = fmaxf(mx, w[n]); }
  float sum = 0.f;
#pragma unroll
  for (int n = 0; n < 9; ++n) { w[n] = __expf(w[n] - mx); sum += w[n]; }
  const float inv = 1.f / sum;
#pragma unroll
  for (int n = 0; n < 9; ++n) w[n] = ok[n] ? w[n] * inv : 0.f;  // OOB v = 0

  // ---- pass 2: pipelined batches; per-batch transpose store; 128B lines ----
  float* __restrict__ tw = &tbuf[wv][0];
  float* __restrict__ ob =
      outg + ((long)(bh >> 3) * HW + y * WW) * DTOT + (bh & 7) * HD;

#define CONSV(S, sl)                                   \
  {                                                    \
    float o[8];                                        \
    _Pragma("unroll") for (int i = 0; i < 8; ++i) {    \
      float acc;                                       \
      acc = w[0] * tapL(b0##S[i]);                     \
      acc = fmaf(w[1], b0##S[i],       acc);           \
      acc = fmaf(w[2], tapR(b0##S[i]), acc);           \
      acc = fmaf(w[3], tapL(b1##S[i]), acc);           \
      acc = fmaf(w[4], b1##S[i],       acc);           \
      acc = fmaf(w[5], tapR(b1##S[i]), acc);           \
      acc = fmaf(w[6], tapL(b2##S[i]), acc);           \
      acc = fmaf(w[7], b2##S[i],       acc);           \
      acc = fmaf(w[8], tapR(b2##S[i]), acc);           \
      o[i] = acc;                                      \
    }                                                  \
    *(float4*)&tw[l * TSTR + (sl) * 4] =               \
        make_float4(o[0], o[1], o[2], o[3]);           \
    *(float4*)&tw[l * TSTR + (sl) * 4 + 4] =           \
        make_float4(o[4], o[5], o[6], o[7]);           \
  }
  // read-out of one 32-ch half: 56px x 8 f4 = 448 f4 = 7 exact rounds.
  // Same-wave LDS ops execute in program order -> safe to overwrite after.
#define READOUT(ch0)                                   \
  _Pragma("unroll") for (int r = 0; r < 7; ++r) {      \
    const int g = r * 64 + l, pxl = g >> 3, slot = g & 7;          \
    const float4 tv = *(const float4*)&tw[pxl * TSTR + slot * 4];  \
    *(float4*)(ob + (long)pxl * DTOT + (ch0) + slot * 4) = tv;     \
  }

  LOADV(B, 8);  CONSV(A, 0);
  LOADV(A, 16); CONSV(B, 2);
  LOADV(B, 24); CONSV(A, 4);
  LOADV(A, 32); CONSV(B, 6);
  READOUT(0);
  LOADV(B, 40); CONSV(A, 0);
  LOADV(A, 48); CONSV(B, 2);
  LOADV(B, 56); CONSV(A, 4);
                CONSV(B, 6);
  READOUT(32);

#undef LOADK
#undef CONSK
#undef LOADV
#undef CONSV
#undef READOUT
}

} // namespace

extern "C" void kernel_launch(void* const* d_in, const int* in_sizes, int n_in,
                              void* d_out, int out_size, void* d_ws, size_t ws_size,
                              hipStream_t stream) {
  const float* q = (const float*)d_in[0];
  const float* k = (const float*)d_in[1];
  const float* v = (const float*)d_in[2];
  float* out = (float*)d_out;

  const int BH = in_sizes[0] / (HD * HW);  // B * 8 heads = 64
  dim3 grid(BH * NB);                       // 1792 = 8 * 224
  adda_fwd<<<grid, 128, 0, stream>>>(q, k, v, out);
}

// Round 15
// 33.810 us; speedup vs baseline: 1.8315x; 1.1812x over previous
//
#include <hip/hip_runtime.h>

// ADDA local attention, K=3, dilation=1, head_dim=64.
// q,k,v = [B=8, d=512, H=56, W=56] fp32 (channel-major), out = [B,H,W,512] fp32.
//
// R15 = R14 + 2-row waves: wave owns rows y,y+1 (lane = x). Per channel,
// 4 k-row loads + 4 v-row loads + 2 q loads serve BOTH output rows
// (5 loads/row vs 7), and middle-row DPP taps are shared (8 DPP/ch/2rows
// vs 12). Ping-pong 8-channel slabs as R14; __launch_bounds__(64,2) lifts
// the VGPR cap so both slabs stay resident.
// Invariants kept: lane=x coalescing, XCD swizzle, wave owns each pixel's
// full 512B output run, zero-padded-unfold masking at softmax only,
// TSTR=36 LDS transpose, same-wave LDS ordering (no barriers).

namespace {

constexpr int HD = 64, HH = 56, WW = 56, HW = HH * WW;
constexpr int CS = HW, DTOT = 512;
constexpr float SCALE = 0.125f;
constexpr int NP   = HH / 2;   // 28 row-pairs
constexpr int TSTR = 36;       // px stride in transpose LDS

// value of this row at x-1 (lane i <- lane i-1): wave_shr:1 = 0x138
__device__ __forceinline__ float tapL(float v) {
  int i = __float_as_int(v);
  return __int_as_float(__builtin_amdgcn_update_dpp(i, i, 0x138, 0xF, 0xF, false));
}
// value of this row at x+1 (lane i <- lane i+1): wave_shl:1 = 0x130
__device__ __forceinline__ float tapR(float v) {
  int i = __float_as_int(v);
  return __int_as_float(__builtin_amdgcn_update_dpp(i, i, 0x130, 0xF, 0xF, false));
}

__global__ __launch_bounds__(64, 2)
void adda_fwd(const float* __restrict__ qg, const float* __restrict__ kg,
              const float* __restrict__ vg, float* __restrict__ outg) {
  __shared__ float tbuf[128 * TSTR];   // 18432 B (rows y: 0..63, y+1: 64..127)

  // XCD-aware bijective swizzle (nwg = 1792 = 8*224): one XCD runs 8 whole
  // bh-planes consecutively -> halo re-reads hit its private L2.
  int wg = (int)blockIdx.x;
  const int nwg = (int)gridDim.x;
  if ((nwg & 7) == 0) wg = (wg & 7) * (nwg >> 3) + (wg >> 3);

  const int pair = wg % NP;
  const int bh   = wg / NP;            // b*8 + head
  const int l    = (int)threadIdx.x;   // 0..63
  const int y    = pair * 2;           // rows y, y+1 (y+1 <= 55 always)
  const int x    = l < WW ? l : WW - 1;  // lanes 56-63 clone x=55 (not stored)

  const long base = (long)bh * HD * HW;
  const int gy0 = (y > 0) ? y - 1 : 0;          // clamped; masked below
  const int gy3 = (y + 2 < HH) ? y + 2 : HH - 1;

  const float* __restrict__ qp0 = qg + base + (long)y * WW + x;
  const float* __restrict__ qp1 = qg + base + (long)(y + 1) * WW + x;
  const float* __restrict__ k0p = kg + base + (long)gy0 * WW + x;
  const float* __restrict__ k1p = kg + base + (long)y * WW + x;
  const float* __restrict__ k2p = kg + base + (long)(y + 1) * WW + x;
  const float* __restrict__ k3p = kg + base + (long)gy3 * WW + x;
  const float* __restrict__ v0p = vg + base + (long)gy0 * WW + x;
  const float* __restrict__ v1p = vg + base + (long)y * WW + x;
  const float* __restrict__ v2p = vg + base + (long)(y + 1) * WW + x;
  const float* __restrict__ v3p = vg + base + (long)gy3 * WW + x;

  float lg[18];
#pragma unroll
  for (int n = 0; n < 18; ++n) lg[n] = 0.f;

  // ---- pass 1: ping-pong 8-channel slabs (48 loads in flight per slab) ----
  float q0A[8], q1A[8], a0A[8], a1A[8], a2A[8], a3A[8];
  float q0B[8], q1B[8], a0B[8], a1B[8], a2B[8], a3B[8];

#define LOADK(S, cb)                                    \
  _Pragma("unroll") for (int i = 0; i < 8; ++i) {       \
    q0##S[i] = qp0[((cb) + i) * CS];                    \
    q1##S[i] = qp1[((cb) + i) * CS];                    \
    a0##S[i] = k0p[((cb) + i) * CS];                    \
    a1##S[i] = k1p[((cb) + i) * CS];                    \
    a2##S[i] = k2p[((cb) + i) * CS];                    \
    a3##S[i] = k3p[((cb) + i) * CS];                    \
  }
#define CONSK(S)                                        \
  _Pragma("unroll") for (int i = 0; i < 8; ++i) {       \
    const float t0l = tapL(a0##S[i]), t0r = tapR(a0##S[i]); \
    const float t1l = tapL(a1##S[i]), t1r = tapR(a1##S[i]); \
    const float t2l = tapL(a2##S[i]), t2r = tapR(a2##S[i]); \
    const float t3l = tapL(a3##S[i]), t3r = tapR(a3##S[i]); \
    const float q0 = q0##S[i], q1 = q1##S[i];           \
    lg[0]  = fmaf(q0, t0l,      lg[0]);                 \
    lg[1]  = fmaf(q0, a0##S[i], lg[1]);                 \
    lg[2]  = fmaf(q0, t0r,      lg[2]);                 \
    lg[3]  = fmaf(q0, t1l,      lg[3]);                 \
    lg[4]  = fmaf(q0, a1##S[i], lg[4]);                 \
    lg[5]  = fmaf(q0, t1r,      lg[5]);                 \
    lg[6]  = fmaf(q0, t2l,      lg[6]);                 \
    lg[7]  = fmaf(q0, a2##S[i], lg[7]);                 \
    lg[8]  = fmaf(q0, t2r,      lg[8]);                 \
    lg[9]  = fmaf(q1, t1l,      lg[9]);                 \
    lg[10] = fmaf(q1, a1##S[i], lg[10]);                \
    lg[11] = fmaf(q1, t1r,      lg[11]);                \
    lg[12] = fmaf(q1, t2l,      lg[12]);                \
    lg[13] = fmaf(q1, a2##S[i], lg[13]);                \
    lg[14] = fmaf(q1, t2r,      lg[14]);                \
    lg[15] = fmaf(q1, t3l,      lg[15]);                \
    lg[16] = fmaf(q1, a3##S[i], lg[16]);                \
    lg[17] = fmaf(q1, t3r,      lg[17]);                \
  }

  LOADK(A, 0);
  LOADK(B, 8);  CONSK(A);
  LOADK(A, 16); CONSK(B);
  LOADK(B, 24); CONSK(A);
  LOADK(A, 32); CONSK(B);
  LOADK(B, 40); CONSK(A);
  LOADK(A, 48); CONSK(B);
  LOADK(B, 56); CONSK(A);

  // ---- first v slab issued early: latency hides under softmax VALU ----
  float b0A[8], b1A[8], b2A[8], b3A[8];
  float b0B[8], b1B[8], b2B[8], b3B[8];
#define LOADV(S, cb)                                    \
  _Pragma("unroll") for (int i = 0; i < 8; ++i) {       \
    b0##S[i] = v0p[((cb) + i) * CS];                    \
    b1##S[i] = v1p[((cb) + i) * CS];                    \
    b2##S[i] = v2p[((cb) + i) * CS];                    \
    b3##S[i] = v3p[((cb) + i) * CS];                    \
  }
  LOADV(A, 0);
  CONSK(B);   // last k slab

  // ---- softmax, both rows (zero-padded unfold: OOB logit = exact 0) ----
  const bool okl = x > 0, okr = x < WW - 1;
  const bool okt0 = y > 0;            // row y's top neighbor
  const bool okb1 = (y + 2) < HH;     // row y+1's bottom neighbor
  const bool ok[18] = {
    okt0 && okl, okt0, okt0 && okr,   // row y: dy=-1
    okl,         true, okr,           // row y: dy=0
    okl,         true, okr,           // row y: dy=+1 (y+1 always in-bounds)
    okl,         true, okr,           // row y+1: dy=-1 (row y, in-bounds)
    okl,         true, okr,           // row y+1: dy=0
    okb1 && okl, okb1, okb1 && okr};  // row y+1: dy=+1
  float w[18];
#pragma unroll
  for (int e = 0; e < 2; ++e) {
    float mx = 0.f;
#pragma unroll
    for (int n = 0; n < 9; ++n) {
      w[e * 9 + n] = ok[e * 9 + n] ? lg[e * 9 + n] * SCALE : 0.f;
      mx = fmaxf(mx, w[e * 9 + n]);
    }
    float sum = 0.f;
#pragma unroll
    for (int n = 0; n < 9; ++n) { w[e * 9 + n] = __expf(w[e * 9 + n] - mx); sum += w[e * 9 + n]; }
    const float inv = 1.f / sum;
#pragma unroll
    for (int n = 0; n < 9; ++n)
      w[e * 9 + n] = ok[e * 9 + n] ? w[e * 9 + n] * inv : 0.f;  // OOB v = 0
  }

  // ---- pass 2: pipelined slabs; per-slab transpose store; 128B lines ----
  float* __restrict__ ob =
      outg + ((long)(bh >> 3) * HW + (long)y * WW) * DTOT + (bh & 7) * HD;

#define CONSV(S, sl)                                    \
  {                                                     \
    float o0[8], o1[8];                                 \
    _Pragma("unroll") for (int i = 0; i < 8; ++i) {     \
      const float t0l = tapL(b0##S[i]), t0r = tapR(b0##S[i]); \
      const float t1l = tapL(b1##S[i]), t1r = tapR(b1##S[i]); \
      const float t2l = tapL(b2##S[i]), t2r = tapR(b2##S[i]); \
      const float t3l = tapL(b3##S[i]), t3r = tapR(b3##S[i]); \
      float a = w[0] * t0l;                             \
      a = fmaf(w[1], b0##S[i], a);                      \
      a = fmaf(w[2], t0r, a);                           \
      a = fmaf(w[3], t1l, a);                           \
      a = fmaf(w[4], b1##S[i], a);                      \
      a = fmaf(w[5], t1r, a);                           \
      a = fmaf(w[6], t2l, a);                           \
      a = fmaf(w[7], b2##S[i], a);                      \
      a = fmaf(w[8], t2r, a);                           \
      o0[i] = a;                                        \
      float c = w[9] * t1l;                             \
      c = fmaf(w[10], b1##S[i], c);                     \
      c = fmaf(w[11], t1r, c);                          \
      c = fmaf(w[12], t2l, c);                          \
      c = fmaf(w[13], b2##S[i], c);                     \
      c = fmaf(w[14], t2r, c);                          \
      c = fmaf(w[15], t3l, c);                          \
      c = fmaf(w[16], b3##S[i], c);                     \
      c = fmaf(w[17], t3r, c);                          \
      o1[i] = c;                                        \
    }                                                   \
    *(float4*)&tbuf[l * TSTR + (sl) * 8]            = make_float4(o0[0], o0[1], o0[2], o0[3]); \
    *(float4*)&tbuf[l * TSTR + (sl) * 8 + 4]        = make_float4(o0[4], o0[5], o0[6], o0[7]); \
    *(float4*)&tbuf[(64 + l) * TSTR + (sl) * 8]     = make_float4(o1[0], o1[1], o1[2], o1[3]); \
    *(float4*)&tbuf[(64 + l) * TSTR + (sl) * 8 + 4] = make_float4(o1[4], o1[5], o1[6], o1[7]); \
  }
  // read-out of one 32-ch run for both rows: 112 px x 8 f4 = 14 exact rounds.
  // Same-wave LDS ops execute in program order -> no barriers needed.
#define READOUT(ch0)                                    \
  _Pragma("unroll") for (int r = 0; r < 14; ++r) {      \
    const int g = r * 64 + l;                           \
    const int pxl = g >> 3, slot = g & 7;               \
    const int lrow = pxl + ((pxl >= 56) ? 8 : 0);       \
    const float4 tv = *(const float4*)&tbuf[lrow * TSTR + slot * 4]; \
    *(float4*)(ob + (long)pxl * DTOT + (ch0) + slot * 4) = tv;      \
  }

  LOADV(B, 8);  CONSV(A, 0);
  LOADV(A, 16); CONSV(B, 1);
  LOADV(B, 24); CONSV(A, 2);
  LOADV(A, 32); CONSV(B, 3);
  LOADV(B, 40); READOUT(0);
  CONSV(A, 0);
  LOADV(A, 48); CONSV(B, 1);
  LOADV(B, 56); CONSV(A, 2);
                CONSV(B, 3);
  READOUT(32);

#undef LOADK
#undef CONSK
#undef LOADV
#undef CONSV
#undef READOUT
}

} // namespace

extern "C" void kernel_launch(void* const* d_in, const int* in_sizes, int n_in,
                              void* d_out, int out_size, void* d_ws, size_t ws_size,
                              hipStream_t stream) {
  const float* q = (const float*)d_in[0];
  const float* k = (const float*)d_in[1];
  const float* v = (const float*)d_in[2];
  float* out = (float*)d_out;

  const int BH = in_sizes[0] / (HD * HW);  // B * 8 heads = 64
  dim3 grid(BH * NP);                       // 1792 = 8 * 224
  adda_fwd<<<grid, 64, 0, stream>>>(q, k, v, out);
}

// Round 17
// 33.577 us; speedup vs baseline: 1.8442x; 1.0070x over previous
//
#include <hip/hip_runtime.h>

// ADDA local attention, K=3, dilation=1, head_dim=64.
// q,k,v = [B=8, d=512, H=56, W=56] fp32 (channel-major), out = [B,H,W,512] fp32.
//
// R17 = R16 with the macro-suffix compile bug fixed (V slabs use sets A/B/C).
// 3-deep slab pipeline: 4-channel slabs, three rotating register sets ->
// 2 slabs (48 loads) in flight during every consume. v prologue issued
// before softmax. Invariants: lane=x coalescing, 2-row waves sharing 4 k/v
// rows, XCD swizzle, wave owns full 512B output run per pixel,
// zero-padded-unfold masking at softmax only, TSTR=36 transpose, no barriers.

namespace {

constexpr int HD = 64, HH = 56, WW = 56, HW = HH * WW;
constexpr int CS = HW, DTOT = 512;
constexpr float SCALE = 0.125f;
constexpr int NP   = HH / 2;   // 28 row-pairs
constexpr int TSTR = 36;       // px stride in transpose LDS

// value of this row at x-1 (lane i <- lane i-1): wave_shr:1 = 0x138
__device__ __forceinline__ float tapL(float v) {
  int i = __float_as_int(v);
  return __int_as_float(__builtin_amdgcn_update_dpp(i, i, 0x138, 0xF, 0xF, false));
}
// value of this row at x+1 (lane i <- lane i+1): wave_shl:1 = 0x130
__device__ __forceinline__ float tapR(float v) {
  int i = __float_as_int(v);
  return __int_as_float(__builtin_amdgcn_update_dpp(i, i, 0x130, 0xF, 0xF, false));
}

__global__ __launch_bounds__(64, 2)
void adda_fwd(const float* __restrict__ qg, const float* __restrict__ kg,
              const float* __restrict__ vg, float* __restrict__ outg) {
  __shared__ float tbuf[128 * TSTR];   // 18432 B (row y: 0..63, row y+1: 64..127)

  // XCD-aware bijective swizzle (nwg = 1792 = 8*224)
  int wg = (int)blockIdx.x;
  const int nwg = (int)gridDim.x;
  if ((nwg & 7) == 0) wg = (wg & 7) * (nwg >> 3) + (wg >> 3);

  const int pair = wg % NP;
  const int bh   = wg / NP;            // b*8 + head
  const int l    = (int)threadIdx.x;   // 0..63
  const int y    = pair * 2;           // rows y, y+1
  const int x    = l < WW ? l : WW - 1;  // lanes 56-63 clone x=55 (not stored)

  const long base = (long)bh * HD * HW;
  const int gy0 = (y > 0) ? y - 1 : 0;          // clamped; masked below
  const int gy3 = (y + 2 < HH) ? y + 2 : HH - 1;

  const float* __restrict__ qp0 = qg + base + (long)y * WW + x;
  const float* __restrict__ qp1 = qg + base + (long)(y + 1) * WW + x;
  const float* __restrict__ k0p = kg + base + (long)gy0 * WW + x;
  const float* __restrict__ k1p = kg + base + (long)y * WW + x;
  const float* __restrict__ k2p = kg + base + (long)(y + 1) * WW + x;
  const float* __restrict__ k3p = kg + base + (long)gy3 * WW + x;
  const float* __restrict__ v0p = vg + base + (long)gy0 * WW + x;
  const float* __restrict__ v1p = vg + base + (long)y * WW + x;
  const float* __restrict__ v2p = vg + base + (long)(y + 1) * WW + x;
  const float* __restrict__ v3p = vg + base + (long)gy3 * WW + x;

  float lg[18];
#pragma unroll
  for (int n = 0; n < 18; ++n) lg[n] = 0.f;

  // ---- 4-channel slabs, 3 rotating sets ----
  float q0A[4], q1A[4], a0A[4], a1A[4], a2A[4], a3A[4];
  float q0B[4], q1B[4], a0B[4], a1B[4], a2B[4], a3B[4];
  float q0C[4], q1C[4], a0C[4], a1C[4], a2C[4], a3C[4];

#define LOADK(S, cb)                                    \
  _Pragma("unroll") for (int i = 0; i < 4; ++i) {       \
    q0##S[i] = qp0[((cb) + i) * CS];                    \
    q1##S[i] = qp1[((cb) + i) * CS];                    \
    a0##S[i] = k0p[((cb) + i) * CS];                    \
    a1##S[i] = k1p[((cb) + i) * CS];                    \
    a2##S[i] = k2p[((cb) + i) * CS];                    \
    a3##S[i] = k3p[((cb) + i) * CS];                    \
  }
#define CONSK(S)                                        \
  _Pragma("unroll") for (int i = 0; i < 4; ++i) {       \
    const float t0l = tapL(a0##S[i]), t0r = tapR(a0##S[i]); \
    const float t1l = tapL(a1##S[i]), t1r = tapR(a1##S[i]); \
    const float t2l = tapL(a2##S[i]), t2r = tapR(a2##S[i]); \
    const float t3l = tapL(a3##S[i]), t3r = tapR(a3##S[i]); \
    const float q0 = q0##S[i], q1 = q1##S[i];           \
    lg[0]  = fmaf(q0, t0l,      lg[0]);                 \
    lg[1]  = fmaf(q0, a0##S[i], lg[1]);                 \
    lg[2]  = fmaf(q0, t0r,      lg[2]);                 \
    lg[3]  = fmaf(q0, t1l,      lg[3]);                 \
    lg[4]  = fmaf(q0, a1##S[i], lg[4]);                 \
    lg[5]  = fmaf(q0, t1r,      lg[5]);                 \
    lg[6]  = fmaf(q0, t2l,      lg[6]);                 \
    lg[7]  = fmaf(q0, a2##S[i], lg[7]);                 \
    lg[8]  = fmaf(q0, t2r,      lg[8]);                 \
    lg[9]  = fmaf(q1, t1l,      lg[9]);                 \
    lg[10] = fmaf(q1, a1##S[i], lg[10]);                \
    lg[11] = fmaf(q1, t1r,      lg[11]);                \
    lg[12] = fmaf(q1, t2l,      lg[12]);                \
    lg[13] = fmaf(q1, a2##S[i], lg[13]);                \
    lg[14] = fmaf(q1, t2r,      lg[14]);                \
    lg[15] = fmaf(q1, t3l,      lg[15]);                \
    lg[16] = fmaf(q1, a3##S[i], lg[16]);                \
    lg[17] = fmaf(q1, t3r,      lg[17]);                \
  }

  float b0A[4], b1A[4], b2A[4], b3A[4];
  float b0B[4], b1B[4], b2B[4], b3B[4];
  float b0C[4], b1C[4], b2C[4], b3C[4];
#define LOADV(S, cb)                                    \
  _Pragma("unroll") for (int i = 0; i < 4; ++i) {       \
    b0##S[i] = v0p[((cb) + i) * CS];                    \
    b1##S[i] = v1p[((cb) + i) * CS];                    \
    b2##S[i] = v2p[((cb) + i) * CS];                    \
    b3##S[i] = v3p[((cb) + i) * CS];                    \
  }

  // ---- pass 1: 16 k slabs, 3-deep ----
  LOADK(A, 0); LOADK(B, 4); LOADK(C, 8);
  CONSK(A); LOADK(A, 12);
  CONSK(B); LOADK(B, 16);
  CONSK(C); LOADK(C, 20);
  CONSK(A); LOADK(A, 24);
  CONSK(B); LOADK(B, 28);
  CONSK(C); LOADK(C, 32);
  CONSK(A); LOADK(A, 36);
  CONSK(B); LOADK(B, 40);
  CONSK(C); LOADK(C, 44);
  CONSK(A); LOADK(A, 48);
  CONSK(B); LOADK(B, 52);
  CONSK(C); LOADK(C, 56);
  CONSK(A); LOADK(A, 60);
  CONSK(B); LOADV(A, 0);
  CONSK(C); LOADV(B, 4);
  CONSK(A); LOADV(C, 8);

  // ---- softmax, both rows (zero-padded unfold: OOB logit = exact 0) ----
  const bool okl = x > 0, okr = x < WW - 1;
  const bool okt0 = y > 0;
  const bool okb1 = (y + 2) < HH;
  const bool ok[18] = {
    okt0 && okl, okt0, okt0 && okr,
    okl,         true, okr,
    okl,         true, okr,
    okl,         true, okr,
    okl,         true, okr,
    okb1 && okl, okb1, okb1 && okr};
  float w[18];
#pragma unroll
  for (int e = 0; e < 2; ++e) {
    float mx = 0.f;
#pragma unroll
    for (int n = 0; n < 9; ++n) {
      w[e * 9 + n] = ok[e * 9 + n] ? lg[e * 9 + n] * SCALE : 0.f;
      mx = fmaxf(mx, w[e * 9 + n]);
    }
    float sum = 0.f;
#pragma unroll
    for (int n = 0; n < 9; ++n) { w[e * 9 + n] = __expf(w[e * 9 + n] - mx); sum += w[e * 9 + n]; }
    const float inv = 1.f / sum;
#pragma unroll
    for (int n = 0; n < 9; ++n)
      w[e * 9 + n] = ok[e * 9 + n] ? w[e * 9 + n] * inv : 0.f;  // OOB v = 0
  }

  // ---- pass 2: 16 v slabs, 3-deep; per-slab f4 transpose store ----
  float* __restrict__ ob =
      outg + ((long)(bh >> 3) * HW + (long)y * WW) * DTOT + (bh & 7) * HD;

#define CONSV(S, sl)                                    \
  {                                                     \
    float o0[4], o1[4];                                 \
    _Pragma("unroll") for (int i = 0; i < 4; ++i) {     \
      const float t0l = tapL(b0##S[i]), t0r = tapR(b0##S[i]); \
      const float t1l = tapL(b1##S[i]), t1r = tapR(b1##S[i]); \
      const float t2l = tapL(b2##S[i]), t2r = tapR(b2##S[i]); \
      const float t3l = tapL(b3##S[i]), t3r = tapR(b3##S[i]); \
      float a = w[0] * t0l;                             \
      a = fmaf(w[1], b0##S[i], a);                      \
      a = fmaf(w[2], t0r, a);                           \
      a = fmaf(w[3], t1l, a);                           \
      a = fmaf(w[4], b1##S[i], a);                      \
      a = fmaf(w[5], t1r, a);                           \
      a = fmaf(w[6], t2l, a);                           \
      a = fmaf(w[7], b2##S[i], a);                      \
      a = fmaf(w[8], t2r, a);                           \
      o0[i] = a;                                        \
      float c = w[9] * t1l;                             \
      c = fmaf(w[10], b1##S[i], c);                     \
      c = fmaf(w[11], t1r, c);                          \
      c = fmaf(w[12], t2l, c);                          \
      c = fmaf(w[13], b2##S[i], c);                     \
      c = fmaf(w[14], t2r, c);                          \
      c = fmaf(w[15], t3l, c);                          \
      c = fmaf(w[16], b3##S[i], c);                     \
      c = fmaf(w[17], t3r, c);                          \
      o1[i] = c;                                        \
    }                                                   \
    *(float4*)&tbuf[l * TSTR + (sl) * 4] =              \
        make_float4(o0[0], o0[1], o0[2], o0[3]);        \
    *(float4*)&tbuf[(64 + l) * TSTR + (sl) * 4] =       \
        make_float4(o1[0], o1[1], o1[2], o1[3]);        \
  }
  // read-out of one 32-ch run for both rows: 112 px x 8 f4 = 14 exact rounds.
#define READOUT(ch0)                                    \
  _Pragma("unroll") for (int r = 0; r < 14; ++r) {      \
    const int g = r * 64 + l;                           \
    const int pxl = g >> 3, slot = g & 7;               \
    const int lrow = pxl + ((pxl >= 56) ? 8 : 0);       \
    const float4 tv = *(const float4*)&tbuf[lrow * TSTR + slot * 4]; \
    *(float4*)(ob + (long)pxl * DTOT + (ch0) + slot * 4) = tv;      \
  }

  CONSV(A, 0); LOADV(A, 12);
  CONSV(B, 1); LOADV(B, 16);
  CONSV(C, 2); LOADV(C, 20);
  CONSV(A, 3); LOADV(A, 24);
  CONSV(B, 4); LOADV(B, 28);
  CONSV(C, 5); LOADV(C, 32);
  CONSV(A, 6); LOADV(A, 36);
  CONSV(B, 7); LOADV(B, 40);
  READOUT(0);
  CONSV(C, 0); LOADV(C, 44);
  CONSV(A, 1); LOADV(A, 48);
  CONSV(B, 2); LOADV(B, 52);
  CONSV(C, 3); LOADV(C, 56);
  CONSV(A, 4); LOADV(A, 60);
  CONSV(B, 5);
  CONSV(C, 6);
  CONSV(A, 7);
  READOUT(32);

#undef LOADK
#undef CONSK
#undef LOADV
#undef CONSV
#undef READOUT
}

} // namespace

extern "C" void kernel_launch(void* const* d_in, const int* in_sizes, int n_in,
                              void* d_out, int out_size, void* d_ws, size_t ws_size,
                              hipStream_t stream) {
  const float* q = (const float*)d_in[0];
  const float* k = (const float*)d_in[1];
  const float* v = (const float*)d_in[2];
  float* out = (float*)d_out;

  const int BH = in_sizes[0] / (HD * HW);  // B * 8 heads = 64
  dim3 grid(BH * NP);                       // 1792 = 8 * 224
  adda_fwd<<<grid, 64, 0, stream>>>(q, k, v, out);
}